// Round 12
// baseline (221.622 us; speedup 1.0000x reference)
//
#include <hip/hip_runtime.h>
#include <math.h>

#define RADIUS    1.3f
#define COARSE    16
#define FINE      4
#define NUM_ATOMS 16
#define DATA_DIM  28
#define N_INTR    217
#define STEPF     0.020634920634920634f

#define CELLS      64            // 4*4*4 fine cells
#define LDS_STRIDE 17            // float4 per cell: 16 atoms + 1 pad
#define RAYS_PB    2
#define NTHREADS   512

__device__ __forceinline__ float sigmoidf_(float x) {
    return 1.0f / (1.0f + expf(-x));
}

__global__ __launch_bounds__(NTHREADS, 4)
void plenoxel_fwd(const float* __restrict__ rays_o,
                  const float* __restrict__ rays_d,
                  const float* __restrict__ cgrid,
                  const float* __restrict__ atoms,
                  float* __restrict__ out,
                  int n_rays)
{
    __shared__ float4 ldsR[RAYS_PB][CELLS * LDS_STRIDE]; // 34816 B folded dicts
    __shared__ float  wtot[8];                           // per-wave scan totals
    __shared__ float  partials[8][5];

    const int tid = threadIdx.x;
    const int g   = tid >> 8;          // ray within block (0..1)
    const int s   = tid & 255;         // sample id
    const int ray = blockIdx.x * RAYS_PB + g;
    const int r0  = blockIdx.x * RAYS_PB;      // first ray of block

    // ---- own-ray setup (redundant per thread; no LDS round-trip) ----
    const float ox = rays_o[ray * 3 + 0], oy = rays_o[ray * 3 + 1], oz = rays_o[ray * 3 + 2];
    const float dx = rays_d[ray * 3 + 0], dy = rays_d[ray * 3 + 1], dz = rays_d[ray * 3 + 2];
    const float sdx = (fabsf(dx) < 1e-9f) ? 1e-9f : dx;
    const float sdy = (fabsf(dy) < 1e-9f) ? 1e-9f : dy;
    const float sdz = (fabsf(dz) < 1e-9f) ? 1e-9f : dz;
    const float t1x = (-RADIUS - ox) / sdx, t2x = (RADIUS - ox) / sdx;
    const float t1y = (-RADIUS - oy) / sdy, t2y = (RADIUS - oy) / sdy;
    const float t1z = (-RADIUS - oz) / sdz, t2z = (RADIUS - oz) / sdz;
    const float tnear = fmaxf(fmaxf(fmaxf(fminf(t1x, t2x), fminf(t1y, t2y)), fminf(t1z, t2z)), 0.0f);
    const float tfar  = fminf(fminf(fmaxf(t1x, t2x), fmaxf(t1y, t2y)), fmaxf(t1z, t2z));
    const float dnorm = sqrtf(dx * dx + dy * dy + dz * dz);

    // ---- sample geometry; ISSUE corner loads FIRST (hidden under the fold) ----
    const float tm   = tnear + ((float)s + 0.5f) * STEPF;
    const bool  mask = (s < N_INTR) && (tm < tfar) && (tfar > tnear);

    float4 gq[8][4];
    float  wcn[8];
    float  p01x = 0.f, p01y = 0.f, p01z = 0.f;

    if (mask) {
        const float px = ox + dx * tm, py = oy + dy * tm, pz = oz + dz * tm;
        p01x = fminf(fmaxf((px + RADIUS) / (2.0f * RADIUS), 0.0f), 0.999999f);
        p01y = fminf(fmaxf((py + RADIUS) / (2.0f * RADIUS), 0.0f), 0.999999f);
        p01z = fminf(fmaxf((pz + RADIUS) / (2.0f * RADIUS), 0.0f), 0.999999f);

        const float ccx = p01x * (COARSE - 1), ccy = p01y * (COARSE - 1), ccz = p01z * (COARSE - 1);
        const float fcx = ccx - floorf(ccx), fcy = ccy - floorf(ccy), fcz = ccz - floorf(ccz);
        int i0x = min(max((int)floorf(ccx), 0), COARSE - 1), i1x = min(i0x + 1, COARSE - 1);
        int i0y = min(max((int)floorf(ccy), 0), COARSE - 1), i1y = min(i0y + 1, COARSE - 1);
        int i0z = min(max((int)floorf(ccz), 0), COARSE - 1), i1z = min(i0z + 1, COARSE - 1);

        #pragma unroll
        for (int cn = 0; cn < 8; ++cn) {
            const int   ix = (cn & 4) ? i1x : i0x;
            const int   iy = (cn & 2) ? i1y : i0y;
            const int   iz = (cn & 1) ? i1z : i0z;
            const float wx = (cn & 4) ? fcx : 1.0f - fcx;
            const float wy = (cn & 2) ? fcy : 1.0f - fcy;
            const float wz = (cn & 1) ? fcz : 1.0f - fcz;
            wcn[cn] = wx * wy * wz;
            const float4* gp = reinterpret_cast<const float4*>(cgrid)
                               + ((((ix << 4) | iy) << 4) | iz) * 4;
            gq[cn][0] = gp[0]; gq[cn][1] = gp[1];
            gq[cn][2] = gp[2]; gq[cn][3] = gp[3];
        }
    }

    // ---- both rays' SH (for the fold); redundant per thread, ~80 VALU ----
    float sh0[9], sh1[9];
    {
        const float d0x = rays_d[r0 * 3 + 0], d0y = rays_d[r0 * 3 + 1], d0z = rays_d[r0 * 3 + 2];
        const float d1x = rays_d[r0 * 3 + 3], d1y = rays_d[r0 * 3 + 4], d1z = rays_d[r0 * 3 + 5];
        const float n0 = 1.0f / sqrtf(d0x * d0x + d0y * d0y + d0z * d0z);
        const float n1 = 1.0f / sqrtf(d1x * d1x + d1y * d1y + d1z * d1z);
        const float ax = d0x * n0, ay = d0y * n0, az = d0z * n0;
        const float bx = d1x * n1, by = d1y * n1, bz = d1z * n1;
        sh0[0] = 0.28209479177387814f;
        sh0[1] = -0.4886025119029199f * ay;
        sh0[2] =  0.4886025119029199f * az;
        sh0[3] = -0.4886025119029199f * ax;
        sh0[4] =  1.0925484305920792f * ax * ay;
        sh0[5] = -1.0925484305920792f * ay * az;
        sh0[6] =  0.31539156525252005f * (2.0f * az * az - ax * ax - ay * ay);
        sh0[7] = -1.0925484305920792f * ax * az;
        sh0[8] =  0.5462742152960396f * (ax * ax - ay * ay);
        sh1[0] = 0.28209479177387814f;
        sh1[1] = -0.4886025119029199f * by;
        sh1[2] =  0.4886025119029199f * bz;
        sh1[3] = -0.4886025119029199f * bx;
        sh1[4] =  1.0925484305920792f * bx * by;
        sh1[5] = -1.0925484305920792f * by * bz;
        sh1[6] =  0.31539156525252005f * (2.0f * bz * bz - bx * bx - by * by);
        sh1[7] = -1.0925484305920792f * bx * bz;
        sh1[8] =  0.5462742152960396f * (bx * bx - by * by);
    }

    // ---- fold: 1024 rows, 2 per thread; atoms read ONCE per block (2 rays) ----
    #pragma unroll
    for (int k = 0; k < 2; ++k) {
        const int row  = tid + k * NTHREADS;
        const float4* arow = reinterpret_cast<const float4*>(atoms) + row * 7;
        float4 fs[7];
        #pragma unroll
        for (int j = 0; j < 7; ++j) fs[j] = arow[j];
        const float f[28] = { fs[0].x, fs[0].y, fs[0].z, fs[0].w,
                              fs[1].x, fs[1].y, fs[1].z, fs[1].w,
                              fs[2].x, fs[2].y, fs[2].z, fs[2].w,
                              fs[3].x, fs[3].y, fs[3].z, fs[3].w,
                              fs[4].x, fs[4].y, fs[4].z, fs[4].w,
                              fs[5].x, fs[5].y, fs[5].z, fs[5].w,
                              fs[6].x, fs[6].y, fs[6].z, fs[6].w };
        const int cell = row >> 4;
        const int atom = row & 15;
        float R0 = 0.0f, G0 = 0.0f, B0 = 0.0f;
        float R1 = 0.0f, G1 = 0.0f, B1 = 0.0f;
        #pragma unroll
        for (int h = 0; h < 9; ++h) {
            R0 += sh0[h] * f[h];  G0 += sh0[h] * f[9 + h];  B0 += sh0[h] * f[18 + h];
            R1 += sh1[h] * f[h];  G1 += sh1[h] * f[9 + h];  B1 += sh1[h] * f[18 + h];
        }
        ldsR[0][cell * LDS_STRIDE + atom] = make_float4(R0, G0, B0, f[27]);
        ldsR[1][cell * LDS_STRIDE + atom] = make_float4(R1, G1, B1, f[27]);
    }
    __syncthreads();

    // ---- stage B: consume corners (already landed) + own dict ----
    float alpha = 0.0f;
    float pr = 0.0f, pg = 0.0f, pb = 0.0f;
    float v = 1.0f;

    if (mask) {
        const float delta = STEPF * dnorm;

        float cf[16];
        #pragma unroll
        for (int a = 0; a < 16; ++a) cf[a] = 0.0f;
        #pragma unroll
        for (int cn = 0; cn < 8; ++cn) {
            const float w = wcn[cn];
            #pragma unroll
            for (int k = 0; k < 4; ++k) {
                const float4 gv = gq[cn][k];
                cf[k * 4 + 0] += w * gv.x;
                cf[k * 4 + 1] += w * gv.y;
                cf[k * 4 + 2] += w * gv.z;
                cf[k * 4 + 3] += w * gv.w;
            }
        }

        const float pfx = p01x * COARSE, pfy = p01y * COARSE, pfz = p01z * COARSE;
        const float lfx = (pfx - floorf(pfx)) * (FINE - 1);
        const float lfy = (pfy - floorf(pfy)) * (FINE - 1);
        const float lfz = (pfz - floorf(pfz)) * (FINE - 1);
        const float ffx = lfx - floorf(lfx), ffy = lfy - floorf(lfy), ffz = lfz - floorf(lfz);
        int j0x = min(max((int)floorf(lfx), 0), FINE - 1), j1x = min(j0x + 1, FINE - 1);
        int j0y = min(max((int)floorf(lfy), 0), FINE - 1), j1y = min(j0y + 1, FINE - 1);
        int j0z = min(max((int)floorf(lfz), 0), FINE - 1), j1z = min(j0z + 1, FINE - 1);

        int   cb[8];
        float wf[8];
        #pragma unroll
        for (int c = 0; c < 8; ++c) {
            const int   jx = (c & 4) ? j1x : j0x;
            const int   jy = (c & 2) ? j1y : j0y;
            const int   jz = (c & 1) ? j1z : j0z;
            const float wx = (c & 4) ? ffx : 1.0f - ffx;
            const float wy = (c & 2) ? ffy : 1.0f - ffy;
            const float wz = (c & 1) ? ffz : 1.0f - ffz;
            wf[c] = wx * wy * wz;
            cb[c] = (((jx << 2) | jy) << 2 | jz) * LDS_STRIDE;
        }

        const float4* dict = ldsR[g];
        float o4x = 0.0f, o4y = 0.0f, o4z = 0.0f, o4w = 0.0f;
        #pragma unroll
        for (int a = 0; a < 16; ++a) {
            float tx = 0.0f, ty = 0.0f, tz = 0.0f, tw = 0.0f;
            #pragma unroll
            for (int c = 0; c < 8; ++c) {
                const float4 vv = dict[cb[c] + a];
                tx += wf[c] * vv.x; ty += wf[c] * vv.y;
                tz += wf[c] * vv.z; tw += wf[c] * vv.w;
            }
            o4x += cf[a] * tx; o4y += cf[a] * ty;
            o4z += cf[a] * tz; o4w += cf[a] * tw;
        }

        const float sigma = fmaxf(o4w, 0.0f);
        alpha = 1.0f - expf(-sigma * delta);
        pr = o4x; pg = o4y; pb = o4z;
    }

    if (s < N_INTR) {
        out[4 * n_rays + ray * N_INTR + s] = alpha;
        v = 1.0f - alpha + 1e-10f;
    }

    // ---- cumprod scan: wave shuffles + one barrier (4 waves per group) ----
    const int lane = tid & 63;
    float incl = v;
    #pragma unroll
    for (int off = 1; off < 64; off <<= 1) {
        const float t = __shfl_up(incl, off);
        if (lane >= off) incl *= t;
    }
    const int wid = tid >> 6;          // 0..7
    if (lane == 63) wtot[wid] = incl;
    __syncthreads();
    float prefix = 1.0f;
    {
        const int w0  = g * 4;
        const int myw = wid & 3;
        #pragma unroll
        for (int q = 0; q < 3; ++q)
            if (q < myw) prefix *= wtot[w0 + q];
    }
    float excl = __shfl_up(incl, 1);
    if (lane == 0) excl = 1.0f;
    const float trans = prefix * excl;
    const float w = alpha * trans;     // alpha==0 for invalid/masked -> w==0

    // ---- reductions (per wave, then per group) ----
    float v0 = w * sigmoidf_(pr);
    float v1 = w * sigmoidf_(pg);
    float v2 = w * sigmoidf_(pb);
    float v3 = w * tm;
    float v4 = w;
    #pragma unroll
    for (int off = 32; off >= 1; off >>= 1) {
        v0 += __shfl_down(v0, off);
        v1 += __shfl_down(v1, off);
        v2 += __shfl_down(v2, off);
        v3 += __shfl_down(v3, off);
        v4 += __shfl_down(v4, off);
    }
    if (lane == 0) {
        partials[wid][0] = v0; partials[wid][1] = v1;
        partials[wid][2] = v2; partials[wid][3] = v3;
        partials[wid][4] = v4;
    }
    __syncthreads();
    if (s == 0) {
        float s0 = 0.0f, s1 = 0.0f, s2 = 0.0f, s3 = 0.0f, s4 = 0.0f;
        #pragma unroll
        for (int q = 0; q < 4; ++q) {
            s0 += partials[g * 4 + q][0]; s1 += partials[g * 4 + q][1];
            s2 += partials[g * 4 + q][2]; s3 += partials[g * 4 + q][3];
            s4 += partials[g * 4 + q][4];
        }
        const float bg = 1.0f - s4;
        out[ray * 3 + 0] = s0 + bg;
        out[ray * 3 + 1] = s1 + bg;
        out[ray * 3 + 2] = s2 + bg;
        out[3 * n_rays + ray] = s3;                        // depth
        if (ray == 0)
            out[4 * n_rays + n_rays * N_INTR] = 0.0f;      // trailing scalar
    }
}

extern "C" void kernel_launch(void* const* d_in, const int* in_sizes, int n_in,
                              void* d_out, int out_size, void* d_ws, size_t ws_size,
                              hipStream_t stream)
{
    const float* rays_o = (const float*)d_in[0];
    const float* rays_d = (const float*)d_in[1];
    const float* cgrid  = (const float*)d_in[2];
    const float* atoms  = (const float*)d_in[3];
    float* out = (float*)d_out;

    const int n_rays = in_sizes[0] / 3;                   // 1024
    const int blocks = (n_rays + RAYS_PB - 1) / RAYS_PB;  // 512
    plenoxel_fwd<<<blocks, NTHREADS, 0, stream>>>(rays_o, rays_d, cgrid, atoms, out, n_rays);
}

// Round 15
// 95.189 us; speedup vs baseline: 2.3282x; 2.3282x over previous
//
#include <hip/hip_runtime.h>
#include <math.h>

#define RADIUS    1.3f
#define COARSE    16
#define FINE      4
#define NUM_ATOMS 16
#define DATA_DIM  28
#define N_INTR    217
#define STEPF     0.020634920634920634f

#define CELLS      64            // 4*4*4 fine cells
#define LDS_STRIDE 17            // float4 per cell: 16 atoms + 1 pad
#define RAYS_PB    2
#define NTHREADS   512

__device__ __forceinline__ float sigmoidf_(float x) {
    return 1.0f / (1.0f + expf(-x));
}

// NOTE: no min-waves arg — round 12 showed __launch_bounds__(512,4) clamps
// VGPRs to 64 and serializes the 32-reg corner staging (165us vs 35us).
__global__ __launch_bounds__(NTHREADS)
void plenoxel_fwd(const float* __restrict__ rays_o,
                  const float* __restrict__ rays_d,
                  const float* __restrict__ cgrid,
                  const float* __restrict__ atoms,
                  float* __restrict__ out,
                  int n_rays)
{
    __shared__ float4 ldsR[RAYS_PB][CELLS * LDS_STRIDE]; // 34816 B folded dicts
    __shared__ float  wtot[8];                           // per-wave scan totals
    __shared__ float  partials[8][5];

    const int tid = threadIdx.x;
    const int g   = tid >> 8;          // ray within block (0..1)
    const int s   = tid & 255;         // sample id
    const int ray = blockIdx.x * RAYS_PB + g;
    const int r0  = blockIdx.x * RAYS_PB;      // first ray of block

    // ---- own-ray setup (redundant per thread; no LDS round-trip) ----
    const float ox = rays_o[ray * 3 + 0], oy = rays_o[ray * 3 + 1], oz = rays_o[ray * 3 + 2];
    const float dx = rays_d[ray * 3 + 0], dy = rays_d[ray * 3 + 1], dz = rays_d[ray * 3 + 2];
    const float sdx = (fabsf(dx) < 1e-9f) ? 1e-9f : dx;
    const float sdy = (fabsf(dy) < 1e-9f) ? 1e-9f : dy;
    const float sdz = (fabsf(dz) < 1e-9f) ? 1e-9f : dz;
    const float t1x = (-RADIUS - ox) / sdx, t2x = (RADIUS - ox) / sdx;
    const float t1y = (-RADIUS - oy) / sdy, t2y = (RADIUS - oy) / sdy;
    const float t1z = (-RADIUS - oz) / sdz, t2z = (RADIUS - oz) / sdz;
    const float tnear = fmaxf(fmaxf(fmaxf(fminf(t1x, t2x), fminf(t1y, t2y)), fminf(t1z, t2z)), 0.0f);
    const float tfar  = fminf(fminf(fmaxf(t1x, t2x), fmaxf(t1y, t2y)), fmaxf(t1z, t2z));
    const float dnorm = sqrtf(dx * dx + dy * dy + dz * dz);

    // ---- sample geometry; ISSUE corner loads FIRST (hidden under the fold) ----
    const float tm   = tnear + ((float)s + 0.5f) * STEPF;
    const bool  mask = (s < N_INTR) && (tm < tfar) && (tfar > tnear);

    float4 gq[8][4];
    float  wcn[8];
    float  p01x = 0.f, p01y = 0.f, p01z = 0.f;

    if (mask) {
        const float px = ox + dx * tm, py = oy + dy * tm, pz = oz + dz * tm;
        p01x = fminf(fmaxf((px + RADIUS) / (2.0f * RADIUS), 0.0f), 0.999999f);
        p01y = fminf(fmaxf((py + RADIUS) / (2.0f * RADIUS), 0.0f), 0.999999f);
        p01z = fminf(fmaxf((pz + RADIUS) / (2.0f * RADIUS), 0.0f), 0.999999f);

        const float ccx = p01x * (COARSE - 1), ccy = p01y * (COARSE - 1), ccz = p01z * (COARSE - 1);
        const float fcx = ccx - floorf(ccx), fcy = ccy - floorf(ccy), fcz = ccz - floorf(ccz);
        int i0x = min(max((int)floorf(ccx), 0), COARSE - 1), i1x = min(i0x + 1, COARSE - 1);
        int i0y = min(max((int)floorf(ccy), 0), COARSE - 1), i1y = min(i0y + 1, COARSE - 1);
        int i0z = min(max((int)floorf(ccz), 0), COARSE - 1), i1z = min(i0z + 1, COARSE - 1);

        #pragma unroll
        for (int cn = 0; cn < 8; ++cn) {
            const int   ix = (cn & 4) ? i1x : i0x;
            const int   iy = (cn & 2) ? i1y : i0y;
            const int   iz = (cn & 1) ? i1z : i0z;
            const float wx = (cn & 4) ? fcx : 1.0f - fcx;
            const float wy = (cn & 2) ? fcy : 1.0f - fcy;
            const float wz = (cn & 1) ? fcz : 1.0f - fcz;
            wcn[cn] = wx * wy * wz;
            const float4* gp = reinterpret_cast<const float4*>(cgrid)
                               + ((((ix << 4) | iy) << 4) | iz) * 4;
            gq[cn][0] = gp[0]; gq[cn][1] = gp[1];
            gq[cn][2] = gp[2]; gq[cn][3] = gp[3];
        }
    }

    // ---- both rays' SH (for the fold); redundant per thread, ~80 VALU ----
    float sh0[9], sh1[9];
    {
        const float d0x = rays_d[r0 * 3 + 0], d0y = rays_d[r0 * 3 + 1], d0z = rays_d[r0 * 3 + 2];
        const float d1x = rays_d[r0 * 3 + 3], d1y = rays_d[r0 * 3 + 4], d1z = rays_d[r0 * 3 + 5];
        const float n0 = 1.0f / sqrtf(d0x * d0x + d0y * d0y + d0z * d0z);
        const float n1 = 1.0f / sqrtf(d1x * d1x + d1y * d1y + d1z * d1z);
        const float ax = d0x * n0, ay = d0y * n0, az = d0z * n0;
        const float bx = d1x * n1, by = d1y * n1, bz = d1z * n1;
        sh0[0] = 0.28209479177387814f;
        sh0[1] = -0.4886025119029199f * ay;
        sh0[2] =  0.4886025119029199f * az;
        sh0[3] = -0.4886025119029199f * ax;
        sh0[4] =  1.0925484305920792f * ax * ay;
        sh0[5] = -1.0925484305920792f * ay * az;
        sh0[6] =  0.31539156525252005f * (2.0f * az * az - ax * ax - ay * ay);
        sh0[7] = -1.0925484305920792f * ax * az;
        sh0[8] =  0.5462742152960396f * (ax * ax - ay * ay);
        sh1[0] = 0.28209479177387814f;
        sh1[1] = -0.4886025119029199f * by;
        sh1[2] =  0.4886025119029199f * bz;
        sh1[3] = -0.4886025119029199f * bx;
        sh1[4] =  1.0925484305920792f * bx * by;
        sh1[5] = -1.0925484305920792f * by * bz;
        sh1[6] =  0.31539156525252005f * (2.0f * bz * bz - bx * bx - by * by);
        sh1[7] = -1.0925484305920792f * bx * bz;
        sh1[8] =  0.5462742152960396f * (bx * bx - by * by);
    }

    // ---- fold: 1024 rows, 2 per thread; atoms read ONCE per block (2 rays) ----
    #pragma unroll
    for (int k = 0; k < 2; ++k) {
        const int row  = tid + k * NTHREADS;
        const float4* arow = reinterpret_cast<const float4*>(atoms) + row * 7;
        float4 fs[7];
        #pragma unroll
        for (int j = 0; j < 7; ++j) fs[j] = arow[j];
        const float f[28] = { fs[0].x, fs[0].y, fs[0].z, fs[0].w,
                              fs[1].x, fs[1].y, fs[1].z, fs[1].w,
                              fs[2].x, fs[2].y, fs[2].z, fs[2].w,
                              fs[3].x, fs[3].y, fs[3].z, fs[3].w,
                              fs[4].x, fs[4].y, fs[4].z, fs[4].w,
                              fs[5].x, fs[5].y, fs[5].z, fs[5].w,
                              fs[6].x, fs[6].y, fs[6].z, fs[6].w };
        const int cell = row >> 4;
        const int atom = row & 15;
        float R0 = 0.0f, G0 = 0.0f, B0 = 0.0f;
        float R1 = 0.0f, G1 = 0.0f, B1 = 0.0f;
        #pragma unroll
        for (int h = 0; h < 9; ++h) {
            R0 += sh0[h] * f[h];  G0 += sh0[h] * f[9 + h];  B0 += sh0[h] * f[18 + h];
            R1 += sh1[h] * f[h];  G1 += sh1[h] * f[9 + h];  B1 += sh1[h] * f[18 + h];
        }
        ldsR[0][cell * LDS_STRIDE + atom] = make_float4(R0, G0, B0, f[27]);
        ldsR[1][cell * LDS_STRIDE + atom] = make_float4(R1, G1, B1, f[27]);
    }
    __syncthreads();

    // ---- stage B: consume corners (already landed) + own dict ----
    float alpha = 0.0f;
    float pr = 0.0f, pg = 0.0f, pb = 0.0f;
    float v = 1.0f;

    if (mask) {
        const float delta = STEPF * dnorm;

        float cf[16];
        #pragma unroll
        for (int a = 0; a < 16; ++a) cf[a] = 0.0f;
        #pragma unroll
        for (int cn = 0; cn < 8; ++cn) {
            const float w = wcn[cn];
            #pragma unroll
            for (int k = 0; k < 4; ++k) {
                const float4 gv = gq[cn][k];
                cf[k * 4 + 0] += w * gv.x;
                cf[k * 4 + 1] += w * gv.y;
                cf[k * 4 + 2] += w * gv.z;
                cf[k * 4 + 3] += w * gv.w;
            }
        }

        const float pfx = p01x * COARSE, pfy = p01y * COARSE, pfz = p01z * COARSE;
        const float lfx = (pfx - floorf(pfx)) * (FINE - 1);
        const float lfy = (pfy - floorf(pfy)) * (FINE - 1);
        const float lfz = (pfz - floorf(pfz)) * (FINE - 1);
        const float ffx = lfx - floorf(lfx), ffy = lfy - floorf(lfy), ffz = lfz - floorf(lfz);
        int j0x = min(max((int)floorf(lfx), 0), FINE - 1), j1x = min(j0x + 1, FINE - 1);
        int j0y = min(max((int)floorf(lfy), 0), FINE - 1), j1y = min(j0y + 1, FINE - 1);
        int j0z = min(max((int)floorf(lfz), 0), FINE - 1), j1z = min(j0z + 1, FINE - 1);

        int   cb[8];
        float wf[8];
        #pragma unroll
        for (int c = 0; c < 8; ++c) {
            const int   jx = (c & 4) ? j1x : j0x;
            const int   jy = (c & 2) ? j1y : j0y;
            const int   jz = (c & 1) ? j1z : j0z;
            const float wx = (c & 4) ? ffx : 1.0f - ffx;
            const float wy = (c & 2) ? ffy : 1.0f - ffy;
            const float wz = (c & 1) ? ffz : 1.0f - ffz;
            wf[c] = wx * wy * wz;
            cb[c] = (((jx << 2) | jy) << 2 | jz) * LDS_STRIDE;
        }

        const float4* dict = ldsR[g];
        float o4x = 0.0f, o4y = 0.0f, o4z = 0.0f, o4w = 0.0f;
        #pragma unroll
        for (int a = 0; a < 16; ++a) {
            float tx = 0.0f, ty = 0.0f, tz = 0.0f, tw = 0.0f;
            #pragma unroll
            for (int c = 0; c < 8; ++c) {
                const float4 vv = dict[cb[c] + a];
                tx += wf[c] * vv.x; ty += wf[c] * vv.y;
                tz += wf[c] * vv.z; tw += wf[c] * vv.w;
            }
            o4x += cf[a] * tx; o4y += cf[a] * ty;
            o4z += cf[a] * tz; o4w += cf[a] * tw;
        }

        const float sigma = fmaxf(o4w, 0.0f);
        alpha = 1.0f - expf(-sigma * delta);
        pr = o4x; pg = o4y; pb = o4z;
    }

    if (s < N_INTR) {
        out[4 * n_rays + ray * N_INTR + s] = alpha;
        v = 1.0f - alpha + 1e-10f;
    }

    // ---- cumprod scan: wave shuffles + one barrier (4 waves per group) ----
    const int lane = tid & 63;
    float incl = v;
    #pragma unroll
    for (int off = 1; off < 64; off <<= 1) {
        const float t = __shfl_up(incl, off);
        if (lane >= off) incl *= t;
    }
    const int wid = tid >> 6;          // 0..7
    if (lane == 63) wtot[wid] = incl;
    __syncthreads();
    float prefix = 1.0f;
    {
        const int w0  = g * 4;
        const int myw = wid & 3;
        #pragma unroll
        for (int q = 0; q < 3; ++q)
            if (q < myw) prefix *= wtot[w0 + q];
    }
    float excl = __shfl_up(incl, 1);
    if (lane == 0) excl = 1.0f;
    const float trans = prefix * excl;
    const float w = alpha * trans;     // alpha==0 for invalid/masked -> w==0

    // ---- reductions (per wave, then per group) ----
    float v0 = w * sigmoidf_(pr);
    float v1 = w * sigmoidf_(pg);
    float v2 = w * sigmoidf_(pb);
    float v3 = w * tm;
    float v4 = w;
    #pragma unroll
    for (int off = 32; off >= 1; off >>= 1) {
        v0 += __shfl_down(v0, off);
        v1 += __shfl_down(v1, off);
        v2 += __shfl_down(v2, off);
        v3 += __shfl_down(v3, off);
        v4 += __shfl_down(v4, off);
    }
    if (lane == 0) {
        partials[wid][0] = v0; partials[wid][1] = v1;
        partials[wid][2] = v2; partials[wid][3] = v3;
        partials[wid][4] = v4;
    }
    __syncthreads();
    if (s == 0) {
        float s0 = 0.0f, s1 = 0.0f, s2 = 0.0f, s3 = 0.0f, s4 = 0.0f;
        #pragma unroll
        for (int q = 0; q < 4; ++q) {
            s0 += partials[g * 4 + q][0]; s1 += partials[g * 4 + q][1];
            s2 += partials[g * 4 + q][2]; s3 += partials[g * 4 + q][3];
            s4 += partials[g * 4 + q][4];
        }
        const float bg = 1.0f - s4;
        out[ray * 3 + 0] = s0 + bg;
        out[ray * 3 + 1] = s1 + bg;
        out[ray * 3 + 2] = s2 + bg;
        out[3 * n_rays + ray] = s3;                        // depth
        if (ray == 0)
            out[4 * n_rays + n_rays * N_INTR] = 0.0f;      // trailing scalar
    }
}

extern "C" void kernel_launch(void* const* d_in, const int* in_sizes, int n_in,
                              void* d_out, int out_size, void* d_ws, size_t ws_size,
                              hipStream_t stream)
{
    const float* rays_o = (const float*)d_in[0];
    const float* rays_d = (const float*)d_in[1];
    const float* cgrid  = (const float*)d_in[2];
    const float* atoms  = (const float*)d_in[3];
    float* out = (float*)d_out;

    const int n_rays = in_sizes[0] / 3;                   // 1024
    const int blocks = (n_rays + RAYS_PB - 1) / RAYS_PB;  // 512
    plenoxel_fwd<<<blocks, NTHREADS, 0, stream>>>(rays_o, rays_d, cgrid, atoms, out, n_rays);
}